// Round 7
// baseline (32.569 us; speedup 1.0000x reference)
//
#include <hip/hip_runtime.h>

#define NFFT 2048
#define TT   512
#define BB   4
#define OUTL 261632        // per-batch trimmed output length

// tile storage: T(i,c) at float2 index i*8 + slot(i,c); rotation spreads banks
__device__ __forceinline__ int TIDX(int i, int c) {
    return i * 8 + ((c + i + (i >> 3)) & 7);
}

__device__ __forceinline__ float2 cmul(float2 a, float2 w) {
    return make_float2(a.x * w.x - a.y * w.y, a.x * w.y + a.y * w.x);
}

// inverse 8-point DFT (+i convention): o[k] = sum_l a[l] e^{+2pi i k l/8}
__device__ __forceinline__ void dft8(const float2 a[8], float2 o[8]) {
    float e0r = a[0].x + a[4].x, e0i = a[0].y + a[4].y;
    float e1r = a[0].x - a[4].x, e1i = a[0].y - a[4].y;
    float e2r = a[2].x + a[6].x, e2i = a[2].y + a[6].y;
    float e3r = a[6].y - a[2].y, e3i = a[2].x - a[6].x;   // i*(a2-a6)
    float E0r = e0r + e2r, E0i = e0i + e2i;
    float E1r = e1r + e3r, E1i = e1i + e3i;
    float E2r = e0r - e2r, E2i = e0i - e2i;
    float E3r = e1r - e3r, E3i = e1i - e3i;
    float f0r = a[1].x + a[5].x, f0i = a[1].y + a[5].y;
    float f1r = a[1].x - a[5].x, f1i = a[1].y - a[5].y;
    float f2r = a[3].x + a[7].x, f2i = a[3].y + a[7].y;
    float f3r = a[7].y - a[3].y, f3i = a[3].x - a[7].x;   // i*(a3-a7)
    float O0r = f0r + f2r, O0i = f0i + f2i;
    float O1r = f1r + f3r, O1i = f1i + f3i;
    float O2r = f0r - f2r, O2i = f0i - f2i;
    float O3r = f1r - f3r, O3i = f1i - f3i;
    const float h = 0.70710678118654752f;
    float W1r = h * (O1r - O1i), W1i = h * (O1r + O1i);   // w^1 * O1
    float W2r = -O2i,            W2i = O2r;               // i * O2
    float W3r = -h * (O3r + O3i), W3i = h * (O3r - O3i);  // w^3 * O3
    o[0] = make_float2(E0r + O0r, E0i + O0i);
    o[1] = make_float2(E1r + W1r, E1i + W1i);
    o[2] = make_float2(E2r + W2r, E2i + W2i);
    o[3] = make_float2(E3r + W3r, E3i + W3i);
    o[4] = make_float2(E0r - O0r, E0i - O0i);
    o[5] = make_float2(E1r - W1r, E1i - W1i);
    o[6] = make_float2(E2r - W2r, E2i - W2i);
    o[7] = make_float2(E3r - W3r, E3i - W3i);
}

// o[k] *= w1^k (powers via in-register cmul chain)
__device__ __forceinline__ void twpow8(float2 o[8], float2 w1) {
    float2 w2 = cmul(w1, w1);
    float2 w3 = cmul(w2, w1);
    float2 w4 = cmul(w2, w2);
    o[1] = cmul(o[1], w1);
    o[2] = cmul(o[2], w2);
    o[3] = cmul(o[3], w3);
    o[4] = cmul(o[4], w4);
    o[5] = cmul(o[5], cmul(w4, w1));
    o[6] = cmul(o[6], cmul(w4, w2));
    o[7] = cmul(o[7], cmul(w4, w3));
}

// Fused iSTFT: one block = 8 consecutive t-columns (one exact-fetch 128KB tile).
// FFT the 8 columns in-place (2 rounds x 4 groups), window into tile.x, then
// OLA: plain stores for interior samples, atomicAdd for the 2-writer seams.
__global__ __launch_bounds__(1024) void istft_k(const float* __restrict__ X,
                                                const float* __restrict__ kc,
                                                const float* __restrict__ ks,
                                                const float* __restrict__ win,
                                                float* __restrict__ out) {
    __shared__ float2 tile[2048 * 8];      // 128 KiB
    __shared__ float2 tw256[256];          // e^{+2pi i m/2048}, m<256

    const int S  = blockIdx.x;
    const int c0 = S * 8;                  // global column base (c = b*512+t)
    const int b  = c0 >> 9;
    const int t0 = c0 & 511;               // multiple of 8
    const int tid = threadIdx.x;           // 0..1023

    if (tid < 256)
        tw256[tid] = make_float2(kc[2048 + tid], ks[2048 + tid]);

    // ---- phase 0: stage tile, full 64B lines per wave-instruction ----
    const float* Xb = X + ((size_t)b * 2048 * 512 + t0) * 2;
    #pragma unroll
    for (int m = 0; m < 8; m++) {
        int f = m * 256 + (tid >> 2);
        int c = (tid & 3) * 2;
        const float4 v = *reinterpret_cast<const float4*>(Xb + ((size_t)f * 512 + c) * 2);
        tile[TIDX(f, c)]     = make_float2(v.x, v.y);
        tile[TIDX(f, c + 1)] = make_float2(v.z, v.w);
    }
    __syncthreads();

    // ---- 2 rounds x 4 columns; group g = tid>>8 owns column c = 4r+g ----
    const int g = tid >> 8;
    const int u = tid & 255;
    #pragma unroll 1
    for (int r = 0; r < 2; r++) {
        const int c = r * 4 + g;
        float2 a[8], o[8];
        // stage A: radix-8, s=1
        #pragma unroll
        for (int l = 0; l < 8; l++) a[l] = tile[TIDX(u + 256 * l, c)];
        __syncthreads();
        dft8(a, o);
        twpow8(o, tw256[u]);
        #pragma unroll
        for (int k = 0; k < 8; k++) tile[TIDX(8 * u + k, c)] = o[k];
        __syncthreads();
        // stage B: radix-8, s=8
        #pragma unroll
        for (int l = 0; l < 8; l++) a[l] = tile[TIDX(u + 256 * l, c)];
        __syncthreads();
        dft8(a, o);
        twpow8(o, tw256[u & ~7]);
        {
            int base = 64 * (u >> 3) + (u & 7);
            #pragma unroll
            for (int k = 0; k < 8; k++) tile[TIDX(base + 8 * k, c)] = o[k];
        }
        __syncthreads();
        // stage C: radix-8, s=64
        #pragma unroll
        for (int l = 0; l < 8; l++) a[l] = tile[TIDX(u + 256 * l, c)];
        __syncthreads();
        dft8(a, o);
        twpow8(o, tw256[u & ~63]);
        {
            int base = 512 * (u >> 6) + (u & 63);
            #pragma unroll
            for (int k = 0; k < 8; k++) tile[TIDX(base + 64 * k, c)] = o[k];
        }
        __syncthreads();
        // stage D: radix-4, s=512, w=1: real parts only, windowed, back into tile.x
        // (each thread reads and writes only its own 8 slots -> no new hazard)
        #pragma unroll
        for (int half = 0; half < 2; half++) {
            int uu = u + 256 * half;
            float2 d0 = tile[TIDX(uu, c)];
            float2 d1 = tile[TIDX(uu + 512, c)];
            float2 d2 = tile[TIDX(uu + 1024, c)];
            float2 d3 = tile[TIDX(uu + 1536, c)];
            float p0 = d0.x + d2.x;
            float p1 = d0.x - d2.x;
            float p2 = d1.x + d3.x;
            float p3 = d3.y - d1.y;          // Re(i*(d1-d3))
            tile[TIDX(uu, c)].x        = (p0 + p2) * win[uu];
            tile[TIDX(uu + 512, c)].x  = (p1 + p3) * win[uu + 512];
            tile[TIDX(uu + 1024, c)].x = (p0 - p2) * win[uu + 1024];
            tile[TIDX(uu + 1536, c)].x = (p1 - p3) * win[uu + 1536];
        }
        // no barrier needed between rounds: round r+1 touches disjoint columns.
    }
    __syncthreads();

    // ---- OLA + normalization. Own region: untrimmed [t0*512, t0*512+4096).
    //      jl in [1536,4096): all 4 frames local -> plain store.
    //      jl in [0,1536) and tail [4096,5632): 2-writer seams -> atomicAdd.
    #pragma unroll
    for (int q = 0; q < 6; q++) {
        int idx = tid + 1024 * q;
        if (q >= 4 && idx - 4096 >= 1536) break;   // tail is only 1536 samples
        int jl = idx;                              // untrimmed offset within region
        int tb_l = jl >> 9;
        int rr = jl & 511;
        int tglob = t0 + tb_l;
        float sum = 0.f, ws = 0.f;
        #pragma unroll
        for (int k = 0; k < 4; k++) {
            int t = tglob - k;                     // global frame time
            int n = rr + (k << 9);
            if (t >= 0 && t < TT) {
                float w = win[n];
                ws += w * w;
                int m = tb_l - k;                  // local frame index
                if (m >= 0 && m < 8) sum += tile[TIDX(n, m)].x;
            }
        }
        float y = sum * (1.0f / 2048.0f);
        if (ws > 1e-10f) y /= ws;
        int jp = t0 * 512 + jl - 1024;             // trimmed output index
        if (jp >= 0 && jp < OUTL) {
            float* dst = out + (size_t)b * OUTL + jp;
            if (jl >= 1536 && jl < 4096) *dst = y;
            else                         atomicAdd(dst, y);
        }
    }
}

extern "C" void kernel_launch(void* const* d_in, const int* in_sizes, int n_in,
                              void* d_out, int out_size, void* d_ws, size_t ws_size,
                              hipStream_t stream) {
    const float* X  = (const float*)d_in[0];
    const float* kc = (const float*)d_in[1];
    const float* ks = (const float*)d_in[2];
    const float* w  = (const float*)d_in[3];
    float* out = (float*)d_out;

    hipMemsetAsync(out, 0, (size_t)out_size * sizeof(float), stream);
    istft_k<<<dim3(BB * TT / 8), dim3(1024), 0, stream>>>(X, kc, ks, w, out);
}

// Round 8
// 29.155 us; speedup vs baseline: 1.1171x; 1.1171x over previous
//
#include <hip/hip_runtime.h>

#define NFFT 2048
#define TT   512
#define BB   4
#define OUTL 261632        // per-batch trimmed output length

// tile: 4 columns as 2 float4 pair-slots per row i, packed into 64B macro-rows
// (rows i, i+1) with a 4-slot rotation; bijective, near-conflict-free for all
// access patterns (A/B/C/D read+write, staging, OLA).
__device__ __forceinline__ int T4(int i, int sp) {
    return ((i >> 1) << 2) | ((2 * (i & 1) + sp + (i >> 1) + (i >> 3)) & 3);
}

__device__ __forceinline__ float2 cmul(float2 a, float2 w) {
    return make_float2(a.x * w.x - a.y * w.y, a.x * w.y + a.y * w.x);
}

// inverse 8-point DFT (+i convention): o[k] = sum_l a[l] e^{+2pi i k l/8}
__device__ __forceinline__ void dft8(const float2 a[8], float2 o[8]) {
    float e0r = a[0].x + a[4].x, e0i = a[0].y + a[4].y;
    float e1r = a[0].x - a[4].x, e1i = a[0].y - a[4].y;
    float e2r = a[2].x + a[6].x, e2i = a[2].y + a[6].y;
    float e3r = a[6].y - a[2].y, e3i = a[2].x - a[6].x;   // i*(a2-a6)
    float E0r = e0r + e2r, E0i = e0i + e2i;
    float E1r = e1r + e3r, E1i = e1i + e3i;
    float E2r = e0r - e2r, E2i = e0i - e2i;
    float E3r = e1r - e3r, E3i = e1i - e3i;
    float f0r = a[1].x + a[5].x, f0i = a[1].y + a[5].y;
    float f1r = a[1].x - a[5].x, f1i = a[1].y - a[5].y;
    float f2r = a[3].x + a[7].x, f2i = a[3].y + a[7].y;
    float f3r = a[7].y - a[3].y, f3i = a[3].x - a[7].x;   // i*(a3-a7)
    float O0r = f0r + f2r, O0i = f0i + f2i;
    float O1r = f1r + f3r, O1i = f1i + f3i;
    float O2r = f0r - f2r, O2i = f0i - f2i;
    float O3r = f1r - f3r, O3i = f1i - f3i;
    const float h = 0.70710678118654752f;
    float W1r = h * (O1r - O1i), W1i = h * (O1r + O1i);   // w^1 * O1
    float W2r = -O2i,            W2i = O2r;               // i * O2
    float W3r = -h * (O3r + O3i), W3i = h * (O3r - O3i);  // w^3 * O3
    o[0] = make_float2(E0r + O0r, E0i + O0i);
    o[1] = make_float2(E1r + W1r, E1i + W1i);
    o[2] = make_float2(E2r + W2r, E2i + W2i);
    o[3] = make_float2(E3r + W3r, E3i + W3i);
    o[4] = make_float2(E0r - O0r, E0i - O0i);
    o[5] = make_float2(E1r - W1r, E1i - W1i);
    o[6] = make_float2(E2r - W2r, E2i - W2i);
    o[7] = make_float2(E3r - W3r, E3i - W3i);
}

// o[k] *= w1^k
__device__ __forceinline__ void twpow8(float2 o[8], float2 w1) {
    float2 w2 = cmul(w1, w1);
    float2 w3 = cmul(w2, w1);
    float2 w4 = cmul(w2, w2);
    o[1] = cmul(o[1], w1);
    o[2] = cmul(o[2], w2);
    o[3] = cmul(o[3], w3);
    o[4] = cmul(o[4], w4);
    o[5] = cmul(o[5], cmul(w4, w1));
    o[6] = cmul(o[6], cmul(w4, w2));
    o[7] = cmul(o[7], cmul(w4, w3));
}

// Fused iSTFT: one block = 4 consecutive t-columns (64KB tile, 2 blocks/CU).
// 2 groups x 256 threads; each group FFTs a COLUMN-PAIR via b128 LDS ops
// (both columns per float4 slot). Then OLA from LDS with seam atomics.
__global__ __launch_bounds__(512, 4) void istft_k(const float* __restrict__ X,
                                                  const float* __restrict__ kc,
                                                  const float* __restrict__ ks,
                                                  const float* __restrict__ win,
                                                  float* __restrict__ out) {
    __shared__ float4 tile[4096];          // 64 KiB
    __shared__ float2 tw[256];             // e^{+2pi i m/2048}, m<256

    const int S  = blockIdx.x;
    // XCD-aware remap: XCD x owns 64 contiguous tiles -> adjacent tiles (which
    // split 64B X-lines) sit on the same XCD/L2.
    const int L  = ((S & 7) << 6) | (S >> 3);
    const int c0 = L * 4;                  // global column base (c = b*512+t)
    const int b  = c0 >> 9;
    const int t0 = c0 & 511;               // multiple of 4
    const int tid = threadIdx.x;           // 0..511

    if (tid < 256)
        tw[tid] = make_float2(kc[2048 + tid], ks[2048 + tid]);

    // ---- staging: 8 float4 loads/thread (pair sp = tid&1) ----
    const float* Xb = X + ((size_t)b * 2048 * 512 + t0) * 2;
    #pragma unroll
    for (int m = 0; m < 8; m++) {
        int f  = m * 256 + (tid >> 1);
        int sp = tid & 1;
        float4 v = *reinterpret_cast<const float4*>(Xb + (size_t)f * 1024 + sp * 4);
        tile[T4(f, sp)] = v;
    }
    __syncthreads();

    const int g = tid >> 8;                // pair index 0/1
    const int u = tid & 255;

    float4 a4[8];
    float2 x0[8], x1[8], o0[8], o1[8];

    // ---- stage A: radix-8, s=1 ----
    #pragma unroll
    for (int l = 0; l < 8; l++) a4[l] = tile[T4(u + 256 * l, g)];
    __syncthreads();
    #pragma unroll
    for (int l = 0; l < 8; l++) {
        x0[l] = make_float2(a4[l].x, a4[l].y);
        x1[l] = make_float2(a4[l].z, a4[l].w);
    }
    dft8(x0, o0); twpow8(o0, tw[u]);
    dft8(x1, o1); twpow8(o1, tw[u]);
    #pragma unroll
    for (int k = 0; k < 8; k++)
        tile[T4(8 * u + k, g)] = make_float4(o0[k].x, o0[k].y, o1[k].x, o1[k].y);
    __syncthreads();

    // ---- stage B: radix-8, s=8 ----
    #pragma unroll
    for (int l = 0; l < 8; l++) a4[l] = tile[T4(u + 256 * l, g)];
    __syncthreads();
    #pragma unroll
    for (int l = 0; l < 8; l++) {
        x0[l] = make_float2(a4[l].x, a4[l].y);
        x1[l] = make_float2(a4[l].z, a4[l].w);
    }
    dft8(x0, o0); twpow8(o0, tw[u & ~7]);
    dft8(x1, o1); twpow8(o1, tw[u & ~7]);
    {
        int base = 64 * (u >> 3) + (u & 7);
        #pragma unroll
        for (int k = 0; k < 8; k++)
            tile[T4(base + 8 * k, g)] = make_float4(o0[k].x, o0[k].y, o1[k].x, o1[k].y);
    }
    __syncthreads();

    // ---- stage C: radix-8, s=64 ----
    #pragma unroll
    for (int l = 0; l < 8; l++) a4[l] = tile[T4(u + 256 * l, g)];
    __syncthreads();
    #pragma unroll
    for (int l = 0; l < 8; l++) {
        x0[l] = make_float2(a4[l].x, a4[l].y);
        x1[l] = make_float2(a4[l].z, a4[l].w);
    }
    dft8(x0, o0); twpow8(o0, tw[u & ~63]);
    dft8(x1, o1); twpow8(o1, tw[u & ~63]);
    {
        int base = 512 * (u >> 6) + (u & 63);
        #pragma unroll
        for (int k = 0; k < 8; k++)
            tile[T4(base + 64 * k, g)] = make_float4(o0[k].x, o0[k].y, o1[k].x, o1[k].y);
    }
    __syncthreads();

    // ---- stage D: radix-4, s=512, w=1: real parts, windowed, in place ----
    #pragma unroll
    for (int half = 0; half < 2; half++) {
        int uu = u + 256 * half;
        float4 d0 = tile[T4(uu, g)];
        float4 d1 = tile[T4(uu + 512, g)];
        float4 d2 = tile[T4(uu + 1024, g)];
        float4 d3 = tile[T4(uu + 1536, g)];
        float p0 = d0.x + d2.x, p1 = d0.x - d2.x;
        float p2 = d1.x + d3.x, p3 = d3.y - d1.y;
        float q0 = d0.z + d2.z, q1 = d0.z - d2.z;
        float q2 = d1.z + d3.z, q3 = d3.w - d1.w;
        float w0 = win[uu], w1 = win[uu + 512], w2 = win[uu + 1024], w3 = win[uu + 1536];
        tile[T4(uu, g)]        = make_float4((p0 + p2) * w0, 0.f, (q0 + q2) * w0, 0.f);
        tile[T4(uu + 512, g)]  = make_float4((p1 + p3) * w1, 0.f, (q1 + q3) * w1, 0.f);
        tile[T4(uu + 1024, g)] = make_float4((p0 - p2) * w2, 0.f, (q0 - q2) * w2, 0.f);
        tile[T4(uu + 1536, g)] = make_float4((p1 - p3) * w3, 0.f, (q1 - q3) * w3, 0.f);
    }
    __syncthreads();

    // ---- OLA + normalization over region [t0*512, t0*512 + 2048+1536) ----
    //      jl in [1536,2048): all 4 frames local -> plain store; else atomic.
    const float* tf = (const float*)tile;
    #pragma unroll 1
    for (int q = 0; q < 7; q++) {
        int jl = tid + 512 * q;
        int tb_l = jl >> 9;
        int rr = jl & 511;
        int tglob = t0 + tb_l;
        float sum = 0.f, ws = 0.f;
        #pragma unroll
        for (int k = 0; k < 4; k++) {
            int t = tglob - k;
            int n = rr + (k << 9);
            if (t >= 0 && t < TT) {
                float w = win[n];
                ws += w * w;
                int m = tb_l - k;
                if (m >= 0 && m < 4)
                    sum += tf[T4(n, m >> 1) * 4 + (m & 1) * 2];
            }
        }
        float y = sum * (1.0f / 2048.0f);
        if (ws > 1e-10f) y /= ws;
        int jp = t0 * 512 + jl - 1024;
        if (jp >= 0 && jp < OUTL) {
            float* dst = out + (size_t)b * OUTL + jp;
            if (jl >= 1536 && jl < 2048) *dst = y;
            else                         atomicAdd(dst, y);
        }
    }
}

extern "C" void kernel_launch(void* const* d_in, const int* in_sizes, int n_in,
                              void* d_out, int out_size, void* d_ws, size_t ws_size,
                              hipStream_t stream) {
    const float* X  = (const float*)d_in[0];
    const float* kc = (const float*)d_in[1];
    const float* ks = (const float*)d_in[2];
    const float* w  = (const float*)d_in[3];
    float* out = (float*)d_out;

    hipMemsetAsync(out, 0, (size_t)out_size * sizeof(float), stream);
    istft_k<<<dim3(BB * TT / 4), dim3(512), 0, stream>>>(X, kc, ks, w, out);
}